// Round 9
// baseline (38.866 us; speedup 1.0000x reference)
//
#include <hip/hip_runtime.h>
#include <math.h>

#define NROWS 65536
#define DDIM 512
#define NUM_CLASSES 1000
#define NSHARD 16
#define SHARD_STRIDE 1040   // floats; 4160 B — off 4KB alignment, float4-aligned
#define ROWS_PER_WAVE 8
#define NBLOCKS (NROWS / (ROWS_PER_WAVE * 4))   // 2048

// --- kernel 1: zero the sharded bins ---
__global__ __launch_bounds__(256) void CenterLoss_zero_ws(float* __restrict__ ws) {
    const int n = NSHARD * SHARD_STRIDE;        // 16640 floats
    for (int i = threadIdx.x + blockIdx.x * 256; i < n; i += 256 * 16)
        ws[i] = 0.0f;
}

__device__ inline float sqdiff4(float4 a, float4 b) {
    float dx = a.x - b.x, dy = a.y - b.y, dz = a.z - b.z, dw = a.w - b.w;
    return fmaf(dx, dx, fmaf(dy, dy, fmaf(dz, dz, dw * dw)));
}

// --- kernel 2: 8 rows/wave (2 chunks of 4), 16-way sharded atomics ---
__global__ __launch_bounds__(256) void CenterLoss_accum(
    const float* __restrict__ x,
    const int* __restrict__ labels,
    const float* __restrict__ centers,
    float* __restrict__ ws)
{
    const int lane = threadIdx.x & 63;
    const int wid  = (blockIdx.x << 2) + (threadIdx.x >> 6);
    const int row0 = wid * ROWS_PER_WAVE;

#pragma unroll
    for (int half = 0; half < 2; ++half) {
        const int r = row0 + half * 4;

        const int l0 = labels[r + 0];
        const int l1 = labels[r + 1];
        const int l2 = labels[r + 2];
        const int l3 = labels[r + 3];

        const float4* __restrict__ x0 = (const float4*)(x + (size_t)(r + 0) * DDIM);
        const float4* __restrict__ x1 = (const float4*)(x + (size_t)(r + 1) * DDIM);
        const float4* __restrict__ x2 = (const float4*)(x + (size_t)(r + 2) * DDIM);
        const float4* __restrict__ x3 = (const float4*)(x + (size_t)(r + 3) * DDIM);
        const float4* __restrict__ c0 = (const float4*)(centers + (size_t)l0 * DDIM);
        const float4* __restrict__ c1 = (const float4*)(centers + (size_t)l1 * DDIM);
        const float4* __restrict__ c2 = (const float4*)(centers + (size_t)l2 * DDIM);
        const float4* __restrict__ c3 = (const float4*)(centers + (size_t)l3 * DDIM);

        // 16 independent float4 loads (8 KB/wave in flight)
        const float4 xa0 = x0[lane], xb0 = x0[lane + 64];
        const float4 xa1 = x1[lane], xb1 = x1[lane + 64];
        const float4 xa2 = x2[lane], xb2 = x2[lane + 64];
        const float4 xa3 = x3[lane], xb3 = x3[lane + 64];
        const float4 ca0 = c0[lane], cb0 = c0[lane + 64];
        const float4 ca1 = c1[lane], cb1 = c1[lane + 64];
        const float4 ca2 = c2[lane], cb2 = c2[lane + 64];
        const float4 ca3 = c3[lane], cb3 = c3[lane + 64];

        float a0 = sqdiff4(xa0, ca0) + sqdiff4(xb0, cb0);
        float a1 = sqdiff4(xa1, ca1) + sqdiff4(xb1, cb1);
        float a2 = sqdiff4(xa2, ca2) + sqdiff4(xb2, cb2);
        float a3 = sqdiff4(xa3, ca3) + sqdiff4(xb3, cb3);

#pragma unroll
        for (int off = 32; off > 0; off >>= 1) {
            a0 += __shfl_xor(a0, off, 64);
            a1 += __shfl_xor(a1, off, 64);
            a2 += __shfl_xor(a2, off, 64);
            a3 += __shfl_xor(a3, off, 64);
        }

        // one atomic instruction, 4 active lanes, each lane -> its own shard
        const float av = (lane == 0) ? a0 : (lane == 1) ? a1 : (lane == 2) ? a2 : a3;
        const int   ab = (lane == 0) ? l0 : (lane == 1) ? l1 : (lane == 2) ? l2 : l3;
        if (lane < 4) {
            const int shard = (wid + lane) & (NSHARD - 1);
            atomicAdd(&ws[shard * SHARD_STRIDE + ab], av);
        }
    }
}

// --- kernel 3: sum 16 shards, sqrt, reduce, scale ---
__global__ __launch_bounds__(256) void CenterLoss_finalize(
    const float* __restrict__ ws, float* __restrict__ out)
{
    const int t = threadIdx.x;
    const int lane = t & 63;

    float s = 0.0f;
    if (t < NUM_CLASSES / 4) {               // 250 threads, 1000 = 250 float4
        float4 v = reinterpret_cast<const float4*>(ws)[t];
#pragma unroll
        for (int sh = 1; sh < NSHARD; ++sh) {
            float4 u = reinterpret_cast<const float4*>(ws + sh * SHARD_STRIDE)[t];
            v.x += u.x; v.y += u.y; v.z += u.z; v.w += u.w;
        }
        s = sqrtf(v.x) + sqrtf(v.y) + sqrtf(v.z) + sqrtf(v.w);
    }
#pragma unroll
    for (int off = 32; off > 0; off >>= 1)
        s += __shfl_xor(s, off, 64);

    __shared__ float partial[4];
    if (lane == 0) partial[t >> 6] = s;
    __syncthreads();
    if (t == 0)
        out[0] = (partial[0] + partial[1] + partial[2] + partial[3])
                 / (float)NUM_CLASSES;
}

extern "C" void kernel_launch(void* const* d_in, const int* in_sizes, int n_in,
                              void* d_out, int out_size, void* d_ws, size_t ws_size,
                              hipStream_t stream) {
    const float* x       = (const float*)d_in[0];
    const int*   labels  = (const int*)d_in[1];
    const float* centers = (const float*)d_in[2];
    float* out = (float*)d_out;
    float* ws  = (float*)d_ws;

    CenterLoss_zero_ws<<<16, 256, 0, stream>>>(ws);
    CenterLoss_accum<<<NBLOCKS, 256, 0, stream>>>(x, labels, centers, ws);
    CenterLoss_finalize<<<1, 256, 0, stream>>>(ws, out);
}

// Round 10
// 38.469 us; speedup vs baseline: 1.0103x; 1.0103x over previous
//
#include <hip/hip_runtime.h>
#include <math.h>

#define NROWS 65536
#define DDIM 512
#define NUM_CLASSES 1000

// ws layout (primary path):
//   [0, 65536)                : per-row squared distances (plain stores)
//   [65536, 65536+16*1000)    : 16 per-block partial bin arrays
#define SQ_OFF 0
#define PART_OFF NROWS
#define NBIN_BLOCKS 16
#define ROWS_PER_BIN_BLOCK (NROWS / NBIN_BLOCKS)   // 4096
#define WS_NEED ((size_t)(NROWS + NBIN_BLOCKS * NUM_CLASSES) * 4)

__device__ inline float sqdiff4(float4 a, float4 b) {
    float dx = a.x - b.x, dy = a.y - b.y, dz = a.z - b.z, dw = a.w - b.w;
    return fmaf(dx, dx, fmaf(dy, dy, fmaf(dz, dz, dw * dw)));
}

// --- A: one wave per row (proven R8 body), NO atomic — plain store sq[row] ---
__global__ __launch_bounds__(256) void CenterLoss_sq(
    const float* __restrict__ x,
    const int* __restrict__ labels,
    const float* __restrict__ centers,
    float* __restrict__ ws)
{
    const int wave = threadIdx.x >> 6;
    const int lane = threadIdx.x & 63;
    const int row  = (blockIdx.x << 2) + wave;
    const int lbl  = labels[row];

    const float4* __restrict__ xr =
        reinterpret_cast<const float4*>(x + (size_t)row * DDIM);
    const float4* __restrict__ cr =
        reinterpret_cast<const float4*>(centers + (size_t)lbl * DDIM);

    const float4 xv0 = xr[lane];
    const float4 xv1 = xr[lane + 64];
    const float4 cv0 = cr[lane];
    const float4 cv1 = cr[lane + 64];

    float acc = sqdiff4(xv0, cv0) + sqdiff4(xv1, cv1);

#pragma unroll
    for (int off = 32; off > 0; off >>= 1)
        acc += __shfl_xor(acc, off, 64);

    if (lane == 0)
        ws[SQ_OFF + row] = acc;          // plain store, no init required
}

// --- B: segment-sum sq by label, block-local LDS bins, plain-store partials ---
__global__ __launch_bounds__(1024) void CenterLoss_bin(
    const int* __restrict__ labels,
    float* __restrict__ ws)
{
    __shared__ float bins[NUM_CLASSES];
    const int t = threadIdx.x;
    if (t < NUM_CLASSES) bins[t] = 0.0f;
    __syncthreads();

    const int base = blockIdx.x * ROWS_PER_BIN_BLOCK;
#pragma unroll
    for (int i = 0; i < ROWS_PER_BIN_BLOCK / 1024; ++i) {
        const int r = base + i * 1024 + t;
        const float v = ws[SQ_OFF + r];
        const int   l = labels[r];
        atomicAdd(&bins[l], v);          // LDS atomic, block-local
    }

    __syncthreads();
    if (t < NUM_CLASSES)
        ws[PART_OFF + blockIdx.x * NUM_CLASSES + t] = bins[t];
}

// --- C: sum 16 partials per class, sqrt, reduce, scale ---
__global__ __launch_bounds__(256) void CenterLoss_finalize(
    const float* __restrict__ ws, float* __restrict__ out)
{
    const int t = threadIdx.x;
    const int lane = t & 63;

    float s = 0.0f;
    if (t < NUM_CLASSES / 4) {           // 250 threads, 1000 = 250 float4
        float4 v = reinterpret_cast<const float4*>(ws + PART_OFF)[t];
#pragma unroll
        for (int b = 1; b < NBIN_BLOCKS; ++b) {
            float4 u = reinterpret_cast<const float4*>(
                           ws + PART_OFF + (size_t)b * NUM_CLASSES)[t];
            v.x += u.x; v.y += u.y; v.z += u.z; v.w += u.w;
        }
        s = sqrtf(v.x) + sqrtf(v.y) + sqrtf(v.z) + sqrtf(v.w);
    }
#pragma unroll
    for (int off = 32; off > 0; off >>= 1)
        s += __shfl_xor(s, off, 64);

    __shared__ float partial[4];
    if (lane == 0) partial[t >> 6] = s;
    __syncthreads();
    if (t == 0)
        out[0] = (partial[0] + partial[1] + partial[2] + partial[3])
                 / (float)NUM_CLASSES;
}

// ---------------- fallback (proven R8, 36.9 µs) if ws too small ----------------
#define NSHARD 8
__global__ __launch_bounds__(256) void CL_zero8(float* __restrict__ ws) {
    const int n = NSHARD * 1024;
    for (int i = threadIdx.x + blockIdx.x * 256; i < n; i += 256 * 8) ws[i] = 0.0f;
}
__global__ __launch_bounds__(256) void CL_accum8(
    const float* __restrict__ x, const int* __restrict__ labels,
    const float* __restrict__ centers, float* __restrict__ ws)
{
    const int wave = threadIdx.x >> 6, lane = threadIdx.x & 63;
    const int row = (blockIdx.x << 2) + wave;
    const int lbl = labels[row];
    const float4* xr = (const float4*)(x + (size_t)row * DDIM);
    const float4* cr = (const float4*)(centers + (size_t)lbl * DDIM);
    const float4 xv0 = xr[lane], xv1 = xr[lane + 64];
    const float4 cv0 = cr[lane], cv1 = cr[lane + 64];
    float acc = sqdiff4(xv0, cv0) + sqdiff4(xv1, cv1);
#pragma unroll
    for (int off = 32; off > 0; off >>= 1) acc += __shfl_xor(acc, off, 64);
    if (lane == 0)
        atomicAdd(&ws[((blockIdx.x & (NSHARD - 1)) << 10) + lbl], acc);
}
__global__ __launch_bounds__(256) void CL_final8(
    const float* __restrict__ ws, float* __restrict__ out)
{
    const int t = threadIdx.x, lane = t & 63;
    float s = 0.0f;
    if (t < NUM_CLASSES / 4) {
        float4 v = reinterpret_cast<const float4*>(ws)[t];
#pragma unroll
        for (int sh = 1; sh < NSHARD; ++sh) {
            float4 u = reinterpret_cast<const float4*>(ws + (sh << 10))[t];
            v.x += u.x; v.y += u.y; v.z += u.z; v.w += u.w;
        }
        s = sqrtf(v.x) + sqrtf(v.y) + sqrtf(v.z) + sqrtf(v.w);
    }
#pragma unroll
    for (int off = 32; off > 0; off >>= 1) s += __shfl_xor(s, off, 64);
    __shared__ float partial[4];
    if (lane == 0) partial[t >> 6] = s;
    __syncthreads();
    if (t == 0)
        out[0] = (partial[0] + partial[1] + partial[2] + partial[3]) / (float)NUM_CLASSES;
}

extern "C" void kernel_launch(void* const* d_in, const int* in_sizes, int n_in,
                              void* d_out, int out_size, void* d_ws, size_t ws_size,
                              hipStream_t stream) {
    const float* x       = (const float*)d_in[0];
    const int*   labels  = (const int*)d_in[1];
    const float* centers = (const float*)d_in[2];
    float* out = (float*)d_out;
    float* ws  = (float*)d_ws;

    if (ws_size >= WS_NEED) {
        CenterLoss_sq<<<NROWS / 4, 256, 0, stream>>>(x, labels, centers, ws);
        CenterLoss_bin<<<NBIN_BLOCKS, 1024, 0, stream>>>(labels, ws);
        CenterLoss_finalize<<<1, 256, 0, stream>>>(ws, out);
    } else {
        CL_zero8<<<8, 256, 0, stream>>>(ws);
        CL_accum8<<<NROWS / 4, 256, 0, stream>>>(x, labels, centers, ws);
        CL_final8<<<1, 256, 0, stream>>>(ws, out);
    }
}